// Round 4
// baseline (728.442 us; speedup 1.0000x reference)
//
#include <hip/hip_runtime.h>

// Com2Net wavefront kernel, round 4.
// Schedule s = 2t + i; one wave per run, lane j owns agents {2j, 2j+1}.
// R=128 waves concurrent -> total time == one wave's 1088 serial macro-steps.
// R3 post-mortem: issue-bound, ~65% of issue cycles are 40 trans ops/step.
// This round:
//   - shared reciprocals: 1/(1+t) for 4 units via ONE v_rcp of the product
//     (+7 muls) -> 20 rcp/step becomes 6/step. exp2 arg clamped at +30 so the
//     4-product stays finite (tanh err ~2e-9).
//   - tanh affine folded into W2: out = (b2+rowsum(W2)) - 2*W2*r  (r=sigmoid')
//   - loop split prologue/steady/epilogue: steady state (960/1088 steps) has
//     all lanes active -> no selects, no low-clamp, unconditional store.

#define T_STEPS 1024
#define N_AGENTS 128

typedef float v2f __attribute__((ext_vector_type(2)));

__device__ __forceinline__ v2f sp(float x) { return (v2f){x, x}; }
__device__ __forceinline__ v2f swap2(v2f a) { return __builtin_shufflevector(a, a, 1, 0); }

// Whole-wave shift-by-1 via DPP; bound_ctrl=1 zeroes the boundary lane,
// which IS the comm[0]/comm[2N+1]==0 semantics.
__device__ __forceinline__ float wave_shr1(float x) {  // lane i <- lane i-1
    int r = __builtin_amdgcn_update_dpp(0, __builtin_bit_cast(int, x),
                                        0x138, 0xF, 0xF, true);
    return __builtin_bit_cast(float, r);
}
__device__ __forceinline__ float wave_shl1(float x) {  // lane i <- lane i+1
    int r = __builtin_amdgcn_update_dpp(0, __builtin_bit_cast(int, x),
                                        0x130, 0xF, 0xF, true);
    return __builtin_bit_cast(float, r);
}

struct Weights {
    v2f w1[4][5];   // w1[c][p] = (W1[2p][c], W1[2p+1][c]) * 2*log2(e)
    v2f b1[5];      // (b1[2p], b1[2p+1]) * 2*log2(e)
    v2f w20[5], w21[5], w22[5];  // -2 * W2 row, packed over hidden pairs
    float b20, b21, b22;         // b2[row] + rowsum(W2[row])
};

// One S2Net eval. inp = [xa, xb, cA, cB], cA = comm[2i] (latest-arriving).
// r_k = 1/(1+exp2(v_k)) with v = 2*log2(e)*preact; tanh = 1-2r folded into W2.
__device__ __forceinline__ void mlp_eval(const Weights& w, float xa, float xb,
                                         float cA, float cB,
                                         float& o0, float& o1, float& o2) {
    v2f d[5];
#pragma unroll
    for (int p = 0; p < 5; ++p) {
        v2f a = __builtin_elementwise_fma(w.w1[0][p], sp(xa), w.b1[p]);
        a = __builtin_elementwise_fma(w.w1[1][p], sp(xb), a);
        a = __builtin_elementwise_fma(w.w1[3][p], sp(cB), a);
        a = __builtin_elementwise_fma(w.w1[2][p], sp(cA), a);
        a = __builtin_elementwise_min(a, (v2f){30.f, 30.f});  // finite 4-products
        v2f t;
        t.x = __builtin_amdgcn_exp2f(a.x);
        t.y = __builtin_amdgcn_exp2f(a.y);
        d[p] = t + (v2f){1.f, 1.f};
    }
    // Shared reciprocals: one rcp per 4 units (pairs 0+1, 2+3), one per pair 4.
    v2f r[5];
    {
        float P0 = d[0].x * d[0].y, P1 = d[1].x * d[1].y;
        float R = __builtin_amdgcn_rcpf(P0 * P1);
        float A = R * P1, B = R * P0;            // A = 1/P0, B = 1/P1
        r[0] = swap2(d[0]) * sp(A);              // (d0.y/P0, d0.x/P0)
        r[1] = swap2(d[1]) * sp(B);
    }
    {
        float P0 = d[2].x * d[2].y, P1 = d[3].x * d[3].y;
        float R = __builtin_amdgcn_rcpf(P0 * P1);
        float A = R * P1, B = R * P0;
        r[2] = swap2(d[2]) * sp(A);
        r[3] = swap2(d[3]) * sp(B);
    }
    {
        float P = d[4].x * d[4].y;
        float R = __builtin_amdgcn_rcpf(P);
        r[4] = swap2(d[4]) * sp(R);
    }
    // Outputs: two interleaved fma chains per output, horizontal add at end.
    v2f a0 = __builtin_elementwise_fma(w.w20[0], r[0], (v2f){w.b20, 0.f});
    v2f a1 = __builtin_elementwise_fma(w.w21[0], r[0], (v2f){w.b21, 0.f});
    v2f a2 = __builtin_elementwise_fma(w.w22[0], r[0], (v2f){w.b22, 0.f});
    v2f b0 = w.w20[1] * r[1];
    v2f b1v = w.w21[1] * r[1];
    v2f b2v = w.w22[1] * r[1];
    a0 = __builtin_elementwise_fma(w.w20[2], r[2], a0);
    a1 = __builtin_elementwise_fma(w.w21[2], r[2], a1);
    a2 = __builtin_elementwise_fma(w.w22[2], r[2], a2);
    b0 = __builtin_elementwise_fma(w.w20[3], r[3], b0);
    b1v = __builtin_elementwise_fma(w.w21[3], r[3], b1v);
    b2v = __builtin_elementwise_fma(w.w22[3], r[3], b2v);
    a0 = __builtin_elementwise_fma(w.w20[4], r[4], a0);
    a1 = __builtin_elementwise_fma(w.w21[4], r[4], a1);
    a2 = __builtin_elementwise_fma(w.w22[4], r[4], a2);
    a0 = a0 + b0; a1 = a1 + b1v; a2 = a2 + b2v;
    o0 = a0.x + a0.y;
    o1 = a1.x + a1.y;
    o2 = a2.x + a2.y;
}

__global__ void __launch_bounds__(64, 1)
com2net_wavefront(const float* __restrict__ runs,
                  const float* __restrict__ W1, const float* __restrict__ b1,
                  const float* __restrict__ W2, const float* __restrict__ b2,
                  float* __restrict__ out)
{
    const int r = blockIdx.x;   // run index
    const int j = threadIdx.x;  // lane 0..63, owns agents 2j and 2j+1

    const float S = 2.8853900817779268f;  // 2*log2(e), folded into layer 1
    Weights w;
#pragma unroll
    for (int p = 0; p < 5; ++p) {
        w.b1[p] = (v2f){b1[2 * p] * S, b1[2 * p + 1] * S};
#pragma unroll
        for (int c = 0; c < 4; ++c)
            w.w1[c][p] = (v2f){W1[(2 * p) * 4 + c] * S, W1[(2 * p + 1) * 4 + c] * S};
        w.w20[p] = (v2f){-2.f * W2[0 * 10 + 2 * p], -2.f * W2[0 * 10 + 2 * p + 1]};
        w.w21[p] = (v2f){-2.f * W2[1 * 10 + 2 * p], -2.f * W2[1 * 10 + 2 * p + 1]};
        w.w22[p] = (v2f){-2.f * W2[2 * 10 + 2 * p], -2.f * W2[2 * 10 + 2 * p + 1]};
    }
    float s0 = 0.f, s1 = 0.f, s2 = 0.f;
#pragma unroll
    for (int k = 0; k < 10; ++k) {
        s0 += W2[k]; s1 += W2[10 + k]; s2 += W2[20 + k];
    }
    w.b20 = b2[0] + s0; w.b21 = b2[1] + s1; w.b22 = b2[2] + s2;

    const float4* __restrict__ xbase =
        (const float4*)(runs + (size_t)r * T_STEPS * N_AGENTS * 2);
    float2* __restrict__ obase =
        (float2*)(out + (size_t)r * T_STEPS * N_AGENTS);

    // c1*/c2* = out1/out2 of this lane's even/odd agent at its latest t.
    float c1e = 0.f, c2e = 0.f, c1o = 0.f, c2o = 0.f;

    auto ldrow = [&](int t) -> float4 {   // clamped both sides (pro/epilogue)
        int tc = t < 0 ? 0 : (t > T_STEPS - 1 ? T_STEPS - 1 : t);
        return xbase[tc * (N_AGENTS / 2) + j];
    };
    auto ldrow_hi = [&](int t) -> float4 {  // steady: t>0 guaranteed
        int tc = t > T_STEPS - 1 ? T_STEPS - 1 : t;
        return xbase[tc * (N_AGENTS / 2) + j];
    };

    // General step (prologue/epilogue): activity-predicated state + store.
    auto step_g = [&](int u, const float4& x) {
        const int t = u - j;
        const bool active = (unsigned)t < (unsigned)T_STEPS;
        float c2pv = wave_shr1(c2o);
        float o0e, o1e, o2e;
        mlp_eval(w, x.x, x.y, c2pv, c1o, o0e, o1e, o2e);
        c1e = active ? o1e : c1e;
        c2e = active ? o2e : c2e;
        float c1pv = wave_shl1(c1e);
        float o0o, o1o, o2o;
        mlp_eval(w, x.z, x.w, c2e, c1pv, o0o, o1o, o2o);
        c1o = active ? o1o : c1o;
        c2o = active ? o2o : c2o;
        if (active) obase[t * (N_AGENTS / 2) + j] = make_float2(o0e, o0o);
    };

    // Steady step: every lane active -> no selects, unconditional store.
    auto step_s = [&](int u, const float4& x) {
        const int t = u - j;
        float c2pv = wave_shr1(c2o);
        float o0e;
        mlp_eval(w, x.x, x.y, c2pv, c1o, o0e, c1e, c2e);
        float c1pv = wave_shl1(c1e);
        float o0o;
        mlp_eval(w, x.z, x.w, c2e, c1pv, o0o, c1o, c2o);
        obase[t * (N_AGENTS / 2) + j] = make_float2(o0e, o0o);
    };

    // Distance-4 register prefetch pipeline, manual unroll-by-4.
    float4 X0 = ldrow(0 - j);
    float4 X1 = ldrow(1 - j);
    float4 X2 = ldrow(2 - j);
    float4 X3 = ldrow(3 - j);

    // Prologue: u in [0,64) — some lanes inactive.
    for (int u = 0; u < 64; u += 4) {
        step_g(u + 0, X0); X0 = ldrow(u + 4 - j);
        step_g(u + 1, X1); X1 = ldrow(u + 5 - j);
        step_g(u + 2, X2); X2 = ldrow(u + 6 - j);
        step_g(u + 3, X3); X3 = ldrow(u + 7 - j);
    }
    // Steady: u in [64,1024) — all lanes active (t = u-j in [1,1023]).
    for (int u = 64; u < 1024; u += 4) {
        step_s(u + 0, X0); X0 = ldrow_hi(u + 4 - j);
        step_s(u + 1, X1); X1 = ldrow_hi(u + 5 - j);
        step_s(u + 2, X2); X2 = ldrow_hi(u + 6 - j);
        step_s(u + 3, X3); X3 = ldrow_hi(u + 7 - j);
    }
    // Epilogue: u in [1024,1088) — trailing lanes drain.
    for (int u = 1024; u < 1024 + 64; u += 4) {
        step_g(u + 0, X0); X0 = ldrow(u + 4 - j);
        step_g(u + 1, X1); X1 = ldrow(u + 5 - j);
        step_g(u + 2, X2); X2 = ldrow(u + 6 - j);
        step_g(u + 3, X3); X3 = ldrow(u + 7 - j);
    }
}

extern "C" void kernel_launch(void* const* d_in, const int* in_sizes, int n_in,
                              void* d_out, int out_size, void* d_ws, size_t ws_size,
                              hipStream_t stream) {
    const float* runs = (const float*)d_in[0];
    const float* W1   = (const float*)d_in[1];
    const float* b1   = (const float*)d_in[2];
    const float* W2   = (const float*)d_in[3];
    const float* b2   = (const float*)d_in[4];
    float* out = (float*)d_out;

    const int R = 128;
    com2net_wavefront<<<R, 64, 0, stream>>>(runs, W1, b1, W2, b2, out);
}

// Round 5
// 704.046 us; speedup vs baseline: 1.0347x; 1.0347x over previous
//
#include <hip/hip_runtime.h>

// Com2Net wavefront kernel, round 5.
// Schedule s = 2t + i; one wave per run, lane j owns agents {2j, 2j+1}.
// R=128 waves concurrent -> total time == one wave's 1088 serial macro-steps.
// R3 calibration: wave's SIMD ~82% issue-busy; ~640 of ~780 issue cyc/step
// are the 40 trans ops (trans ~ 12-16 cyc/wave64). R4's grouped-rcp regressed
// via runtime swaps + longer recurrence chain. R5 = grouped rcp done clean:
//   - pair-internal SWAP AT SETUP (W1/b1 packed (2p+1,2p)) so r = sp(1/P)*d
//     needs no runtime swap; W2 packed natural (pair 4 swapped, see below)
//   - groups {0,1},{2,3} share one rcp via product; pair 4 uses direct
//     per-unit rcp so the recurrence-critical tail keeps R3's short chain
//   - tanh affine folded into W2; comm-independent preact hoisted above DPP

#define T_STEPS 1024
#define N_AGENTS 128

typedef float v2f __attribute__((ext_vector_type(2)));

__device__ __forceinline__ v2f sp(float x) { return (v2f){x, x}; }

// Whole-wave shift-by-1 via DPP; bound_ctrl=1 zeroes the boundary lane,
// which IS the comm[0]/comm[2N+1]==0 semantics.
__device__ __forceinline__ float wave_shr1(float x) {  // lane i <- lane i-1
    int r = __builtin_amdgcn_update_dpp(0, __builtin_bit_cast(int, x),
                                        0x138, 0xF, 0xF, true);
    return __builtin_bit_cast(float, r);
}
__device__ __forceinline__ float wave_shl1(float x) {  // lane i <- lane i+1
    int r = __builtin_amdgcn_update_dpp(0, __builtin_bit_cast(int, x),
                                        0x130, 0xF, 0xF, true);
    return __builtin_bit_cast(float, r);
}

struct Weights {
    // Pair p packs units (2p+1, 2p)  [SWAPPED] for layer 1:
    v2f w1c0[5], w1c1[5], w1c2[5], w1c3[5];  // per input column, * 2*log2(e)
    v2f b1p[5];                              // * 2*log2(e)
    // Layer 2: -2*W2, pairs 0..3 packed natural (2p, 2p+1); pair 4 SWAPPED
    // (9, 8) to match the direct-rcp output order.
    v2f w20[5], w21[5], w22[5];
    float b20, b21, b22;                     // b2[r] + rowsum(W2[r])
};

// One S2Net eval. stat[p] = b1 + W1col0*xa + W1col1*xb (comm-independent).
// cA = comm[2i] (latest-arriving -> consumed by the last preact fma).
// d_u = 1 + exp2(v_u); r_u = 1/d_u; out = b2'' - 2*W2*r (fold).
__device__ __forceinline__ void mlp_eval(const Weights& w, const v2f stat[5],
                                         float cA, float cB,
                                         float& o0, float& o1, float& o2) {
    v2f d[5];
#pragma unroll
    for (int p = 0; p < 5; ++p) {
        v2f a = __builtin_elementwise_fma(w.w1c3[p], sp(cB), stat[p]);
        a = __builtin_elementwise_fma(w.w1c2[p], sp(cA), a);
        a = __builtin_elementwise_min(a, (v2f){30.f, 30.f});  // finite products
        v2f t;
        t.x = __builtin_amdgcn_exp2f(a.x);
        t.y = __builtin_amdgcn_exp2f(a.y);
        d[p] = t + (v2f){1.f, 1.f};
    }
    // Shared reciprocals, swap-free because pairs were packed (2p+1, 2p):
    // r_pair_natural = sp(1/P_pair) * d_pair.
    float P0 = d[0].x * d[0].y, P1 = d[1].x * d[1].y;
    float R01 = __builtin_amdgcn_rcpf(P0 * P1);
    v2f r0 = sp(R01 * P1) * d[0];
    v2f r1 = sp(R01 * P0) * d[1];
    float P2 = d[2].x * d[2].y, P3 = d[3].x * d[3].y;
    float R23 = __builtin_amdgcn_rcpf(P2 * P3);
    v2f r2 = sp(R23 * P3) * d[2];
    v2f r3 = sp(R23 * P2) * d[3];
    // Pair 4: direct rcp -> short recurrence tail (exp->add->rcp->fma), and
    // output order (1/d.x, 1/d.y) = (r9, r8) matches W2 pair-4 swapped pack.
    v2f r4;
    r4.x = __builtin_amdgcn_rcpf(d[4].x);
    r4.y = __builtin_amdgcn_rcpf(d[4].y);

    // Row 1 first (feeds the DPP for the next phase), then row 2, then row 0.
    v2f a1 = __builtin_elementwise_fma(w.w21[0], r0, (v2f){w.b21, 0.f});
    v2f c1 = w.w21[1] * r1;
    a1 = __builtin_elementwise_fma(w.w21[2], r2, a1);
    c1 = __builtin_elementwise_fma(w.w21[3], r3, c1);
    a1 = __builtin_elementwise_fma(w.w21[4], r4, a1);
    a1 = a1 + c1;
    o1 = a1.x + a1.y;

    v2f a2 = __builtin_elementwise_fma(w.w22[0], r0, (v2f){w.b22, 0.f});
    v2f c2 = w.w22[1] * r1;
    a2 = __builtin_elementwise_fma(w.w22[2], r2, a2);
    c2 = __builtin_elementwise_fma(w.w22[3], r3, c2);
    a2 = __builtin_elementwise_fma(w.w22[4], r4, a2);
    a2 = a2 + c2;
    o2 = a2.x + a2.y;

    v2f a0 = __builtin_elementwise_fma(w.w20[0], r0, (v2f){w.b20, 0.f});
    v2f c0 = w.w20[1] * r1;
    a0 = __builtin_elementwise_fma(w.w20[2], r2, a0);
    c0 = __builtin_elementwise_fma(w.w20[3], r3, c0);
    a0 = __builtin_elementwise_fma(w.w20[4], r4, a0);
    a0 = a0 + c0;
    o0 = a0.x + a0.y;
}

__global__ void __launch_bounds__(64, 1)
com2net_wavefront(const float* __restrict__ runs,
                  const float* __restrict__ W1, const float* __restrict__ b1,
                  const float* __restrict__ W2, const float* __restrict__ b2,
                  float* __restrict__ out)
{
    const int r = blockIdx.x;   // run index
    const int j = threadIdx.x;  // lane 0..63, owns agents 2j and 2j+1

    const float S = 2.8853900817779268f;  // 2*log2(e), folded into layer 1
    Weights w;
#pragma unroll
    for (int p = 0; p < 5; ++p) {
        const int hi = 2 * p + 1, lo = 2 * p;     // layer-1 pair order (hi, lo)
        w.b1p[p] = (v2f){b1[hi] * S, b1[lo] * S};
        w.w1c0[p] = (v2f){W1[hi * 4 + 0] * S, W1[lo * 4 + 0] * S};
        w.w1c1[p] = (v2f){W1[hi * 4 + 1] * S, W1[lo * 4 + 1] * S};
        w.w1c2[p] = (v2f){W1[hi * 4 + 2] * S, W1[lo * 4 + 2] * S};
        w.w1c3[p] = (v2f){W1[hi * 4 + 3] * S, W1[lo * 4 + 3] * S};
    }
#pragma unroll
    for (int p = 0; p < 4; ++p) {                 // layer-2 pairs 0..3 natural
        w.w20[p] = (v2f){-2.f * W2[0 * 10 + 2 * p], -2.f * W2[0 * 10 + 2 * p + 1]};
        w.w21[p] = (v2f){-2.f * W2[1 * 10 + 2 * p], -2.f * W2[1 * 10 + 2 * p + 1]};
        w.w22[p] = (v2f){-2.f * W2[2 * 10 + 2 * p], -2.f * W2[2 * 10 + 2 * p + 1]};
    }
    // layer-2 pair 4 swapped: (unit 9, unit 8)
    w.w20[4] = (v2f){-2.f * W2[0 * 10 + 9], -2.f * W2[0 * 10 + 8]};
    w.w21[4] = (v2f){-2.f * W2[1 * 10 + 9], -2.f * W2[1 * 10 + 8]};
    w.w22[4] = (v2f){-2.f * W2[2 * 10 + 9], -2.f * W2[2 * 10 + 8]};
    float s0 = 0.f, s1 = 0.f, s2 = 0.f;
#pragma unroll
    for (int k = 0; k < 10; ++k) {
        s0 += W2[k]; s1 += W2[10 + k]; s2 += W2[20 + k];
    }
    w.b20 = b2[0] + s0; w.b21 = b2[1] + s1; w.b22 = b2[2] + s2;

    const float4* __restrict__ xbase =
        (const float4*)(runs + (size_t)r * T_STEPS * N_AGENTS * 2);
    float2* __restrict__ obase =
        (float2*)(out + (size_t)r * T_STEPS * N_AGENTS);

    // c1*/c2* = out1/out2 of this lane's even/odd agent at its latest t.
    float c1e = 0.f, c2e = 0.f, c1o = 0.f, c2o = 0.f;

    auto ldrow = [&](int t) -> float4 {   // clamped both sides
        int tc = t < 0 ? 0 : (t > T_STEPS - 1 ? T_STEPS - 1 : t);
        return xbase[tc * (N_AGENTS / 2) + j];
    };
    auto ldrow_hi = [&](int t) -> float4 {  // steady: t >= 0 guaranteed
        int tc = t > T_STEPS - 1 ? T_STEPS - 1 : t;
        return xbase[tc * (N_AGENTS / 2) + j];
    };

    // Comm-independent preact terms for both phases (hoisted above the DPPs).
    v2f statE[5], statO[5];
    auto mkstat = [&](const float4& x) {
#pragma unroll
        for (int p = 0; p < 5; ++p) {
            statE[p] = __builtin_elementwise_fma(
                w.w1c0[p], sp(x.x),
                __builtin_elementwise_fma(w.w1c1[p], sp(x.y), w.b1p[p]));
            statO[p] = __builtin_elementwise_fma(
                w.w1c0[p], sp(x.z),
                __builtin_elementwise_fma(w.w1c1[p], sp(x.w), w.b1p[p]));
        }
    };

    // General step (prologue/epilogue): activity-predicated state + store.
    auto step_g = [&](int u, const float4& x) {
        const int t = u - j;
        const bool active = (unsigned)t < (unsigned)T_STEPS;
        mkstat(x);
        float c2pv = wave_shr1(c2o);
        float o0e, o1e, o2e;
        mlp_eval(w, statE, c2pv, c1o, o0e, o1e, o2e);
        c1e = active ? o1e : c1e;
        c2e = active ? o2e : c2e;
        float c1pv = wave_shl1(c1e);
        float o0o, o1o, o2o;
        mlp_eval(w, statO, c2e, c1pv, o0o, o1o, o2o);
        c1o = active ? o1o : c1o;
        c2o = active ? o2o : c2o;
        if (active) obase[t * (N_AGENTS / 2) + j] = make_float2(o0e, o0o);
    };

    // Steady step: every lane active -> no selects, unconditional store.
    auto step_s = [&](int u, const float4& x) {
        const int t = u - j;
        mkstat(x);
        float c2pv = wave_shr1(c2o);
        float o0e;
        mlp_eval(w, statE, c2pv, c1o, o0e, c1e, c2e);
        float c1pv = wave_shl1(c1e);
        float o0o;
        mlp_eval(w, statO, c2e, c1pv, o0o, c1o, c2o);
        obase[t * (N_AGENTS / 2) + j] = make_float2(o0e, o0o);
    };

    // Distance-4 register prefetch pipeline, manual unroll-by-4.
    float4 X0 = ldrow(0 - j);
    float4 X1 = ldrow(1 - j);
    float4 X2 = ldrow(2 - j);
    float4 X3 = ldrow(3 - j);

    // Prologue: u in [0,64) — leading lanes inactive.
    for (int u = 0; u < 64; u += 4) {
        step_g(u + 0, X0); X0 = ldrow(u + 4 - j);
        step_g(u + 1, X1); X1 = ldrow(u + 5 - j);
        step_g(u + 2, X2); X2 = ldrow(u + 6 - j);
        step_g(u + 3, X3); X3 = ldrow(u + 7 - j);
    }
    // Steady: u in [64,1024) — all lanes active (t = u-j in [1,1023]).
    for (int u = 64; u < 1024; u += 4) {
        step_s(u + 0, X0); X0 = ldrow_hi(u + 4 - j);
        step_s(u + 1, X1); X1 = ldrow_hi(u + 5 - j);
        step_s(u + 2, X2); X2 = ldrow_hi(u + 6 - j);
        step_s(u + 3, X3); X3 = ldrow_hi(u + 7 - j);
    }
    // Epilogue: u in [1024,1088) — trailing lanes drain.
    for (int u = 1024; u < 1024 + 64; u += 4) {
        step_g(u + 0, X0); X0 = ldrow(u + 4 - j);
        step_g(u + 1, X1); X1 = ldrow(u + 5 - j);
        step_g(u + 2, X2); X2 = ldrow(u + 6 - j);
        step_g(u + 3, X3); X3 = ldrow(u + 7 - j);
    }
}

extern "C" void kernel_launch(void* const* d_in, const int* in_sizes, int n_in,
                              void* d_out, int out_size, void* d_ws, size_t ws_size,
                              hipStream_t stream) {
    const float* runs = (const float*)d_in[0];
    const float* W1   = (const float*)d_in[1];
    const float* b1   = (const float*)d_in[2];
    const float* W2   = (const float*)d_in[3];
    const float* b2   = (const float*)d_in[4];
    float* out = (float*)d_out;

    const int R = 128;
    com2net_wavefront<<<R, 64, 0, stream>>>(runs, W1, b1, W2, b2, out);
}